// Round 7
// baseline (487.430 us; speedup 1.0000x reference)
//
#include <hip/hip_runtime.h>

// ---------------------------------------------------------------------------
// YOLOv3 post-processing pipeline (round 13):
//   K1 decode : boxes + conf_q (r6/r10 verbatim, proven)
//   K2 topk   : sample-threshold single-scan select.
//               - sample 1024 keys -> 4096-bin LDS hist -> threshold t
//               - ONE streaming keygen pass; keys >= t-2 collected with
//                 EXACT rescore computed from live registers (no re-reads)
//               - exactness check: cntA(>=t) >= 100 && collected <= 2048,
//                 else bounded retry with adjusted t (prob ~3e-5/row)
//               Removes: 29M-LDS-atomic histogram, the full second pass,
//               collect's scattered gathers. (r12's 68KB LDS staging and
//               its occupancy collapse reverted.)
//   K3 final  : per-image top-100 of 8000 (verbatim)
//   Ledger: measured total = sum(kernels) + ~100us harness floor.
// ---------------------------------------------------------------------------

#define NTOT   22743      // 3*(19^2 + 38^2 + 76^2)
#define NCLS   80
#define TOPK   100
#define KPAD   22752      // row stride for conf_q (16B aligned, 8-div)
#define NG2    2166       // 8-key groups in layer 2 (17328 keys)
#define Q_L1   17328
#define Q_L0   21660
#define SAMPLE_K 24       // sample order statistic -> E[collected] ~ 530
#define BUFCAP 2048
#define SCORE_THR 0.2f
#define NMS_THR   0.3f

__device__ __forceinline__ float sig_exact(float x) {
    return 1.0f / (1.0f + expf(-x));          // precise OCML expf + IEEE div
}
__device__ __forceinline__ float sig_fast(float x) {
    // monotone surrogate, rel err ~1e-6; u16-key deviation <= 1 unit,
    // covered by the t-2 collect margin
    return __builtin_amdgcn_rcpf(1.0f + __expf(-x));
}

// -------------------------- K1: decode (plane-major) ----------------------
__global__ __launch_bounds__(256) void k_decode(
    const float* __restrict__ f0, const float* __restrict__ f1,
    const float* __restrict__ f2, const float* __restrict__ anchors,
    const float* __restrict__ imshape, float4* __restrict__ boxes,
    float* __restrict__ conf_q, int total) {
    int gid = blockIdx.x * 256 + threadIdx.x;
    if (gid >= total) return;
    int b = gid / NTOT; int p = gid - b * NTOT;

    const float* f; int ghw, gw, l, off, a, s;
    if (p < 1083)      { f=f0; off=0;    ghw=361;  gw=19; l=0; int r=p;      a=r/361;  s=r-a*361;  }
    else if (p < 5415) { f=f1; off=1083; ghw=1444; gw=38; l=1; int r=p-1083; a=r/1444; s=r-a*1444; }
    else               { f=f2; off=5415; ghw=5776; gw=76; l=2; int r=p-5415; a=r/5776; s=r-a*5776; }
    int y = s / gw, x = s - y * gw;

    const float* q = f + ((size_t)(b * 255 + a * 85) * ghw + s);
    float tx = q[0], ty = q[ghw], tw = q[2*ghw], th = q[3*ghw], tc = q[4*ghw];

    int arow = (2 - l) * 3 + a;
    float aw = anchors[arow * 2], ah = anchors[arow * 2 + 1];
    float imh = imshape[0], imw = imshape[1];
    float gf = (float)gw;                       // gh == gw for all layers

    float bxx = (sig_exact(tx) + (float)x) / gf;
    float bxy = (sig_exact(ty) + (float)y) / gf;
    float bw  = expf(tw) * aw / 608.0f;
    float bh  = expf(th) * ah / 608.0f;

    float r  = fminf(608.0f / imh, 608.0f / imw);
    float nh = rintf(imh * r), nw = rintf(imw * r);
    float offy = (608.0f - nh) / 2.0f / 608.0f;
    float offx = (608.0f - nw) / 2.0f / 608.0f;
    float scy = 608.0f / nh, scx = 608.0f / nw;

    float cy = (bxy - offy) * scy;
    float cx = (bxx - offx) * scx;
    float hh = bh * scy, ww = bw * scx;

    int n = off + 3 * s + a;                    // anchor-major output index
    boxes[(size_t)b * NTOT + n] =
        make_float4((cy - hh / 2.0f) * imh, (cx - ww / 2.0f) * imw,
                    (cy + hh / 2.0f) * imh, (cx + ww / 2.0f) * imw);
    int qi = (l == 2) ? (a * 5776 + s)
           : (l == 1) ? (Q_L1 + a * 1444 + s)
                      : (Q_L0 + a * 361 + s);
    conf_q[(size_t)b * KPAD + qi] = sig_exact(tc);
}

// ------------------ shared select helpers ---------------------------------
__device__ void find_pivot(unsigned* hist, int H, unsigned target,
                           unsigned* suf, unsigned* sh_p, unsigned* sh_above) {
    const int tid = threadIdx.x;
    const int per = H >> 8;
    if (tid < 256) {
        unsigned acc = 0;
        for (int u = 0; u < per; ++u) acc += hist[tid * per + u];
        suf[tid] = acc;
    }
    __syncthreads();
    for (int off = 1; off < 256; off <<= 1) {
        unsigned v = 0;
        if (tid < 256) v = (tid + off < 256) ? suf[tid + off] : 0u;
        __syncthreads();
        if (tid < 256) suf[tid] += v;
        __syncthreads();
    }
    if (tid < 256) {
        unsigned mysuf = suf[tid];
        unsigned nxt = (tid == 255) ? 0u : suf[tid + 1];
        if (mysuf >= target && nxt < target) {
            unsigned above = nxt;
            for (int h = tid * per + per - 1; h >= tid * per; --h) {
                unsigned c2 = above + hist[h];
                if (c2 >= target) { *sh_p = (unsigned)h; *sh_above = above; break; }
                above = c2;
            }
        }
    }
    __syncthreads();
}

// q -> logit address decode (sample phase only)
__device__ __forceinline__ float load_logit(int b, int c, int q,
    const float* __restrict__ f0, const float* __restrict__ f1,
    const float* __restrict__ f2) {
    int a, s, ghw; const float* f;
    if (q < Q_L1)      { f = f2; ghw = 5776; a = q / 5776;  s = q - a * 5776; }
    else if (q < Q_L0) { f = f1; ghw = 1444; int r = q - Q_L1; a = r / 1444; s = r - a * 1444; }
    else               { f = f0; ghw = 361;  int r = q - Q_L0; a = r / 361;  s = r - a * 361; }
    return f[((size_t)(b * 255 + a * 85 + 5 + c)) * ghw + s];
}

__device__ __forceinline__ void try_collect(
    float cf, float lg, int n, unsigned tm, unsigned t,
    unsigned long long* buf, unsigned* sh_cnt, unsigned* sh_cntA) {
    unsigned fk = __float_as_uint(cf * sig_fast(lg)) >> 16;
    if (fk >= tm) {
        if (fk >= t) atomicAdd(sh_cntA, 1u);
        unsigned slot = atomicAdd(sh_cnt, 1u);
        if (slot < BUFCAP) {
            float sce = cf * sig_exact(lg);   // exact rescore, from registers
            buf[slot] = (((unsigned long long)__float_as_uint(sce)) << 32)
                        | (unsigned)(~n);
        }
    }
}

// -------------------------- K2: sample+scan topk + NMS --------------------
__global__ __launch_bounds__(512, 4) void k_topk(
    const float* __restrict__ f0, const float* __restrict__ f1,
    const float* __restrict__ f2, const float* __restrict__ conf_q,
    const float4* __restrict__ boxes, float4* __restrict__ top_b,
    float* __restrict__ cand) {
    __shared__ unsigned int shist[4096];           // 16 KB sample hist (u32)
    __shared__ unsigned long long buf[BUFCAP];     // 16 KB
    __shared__ unsigned int wsum[4];
    __shared__ float sb_y1[TOPK], sb_x1[TOPK], sb_y2[TOPK], sb_x2[TOPK], sb_s[TOPK];
    __shared__ unsigned int sh_t, sh_cnt, sh_cntA;

    const int tid = threadIdx.x;
    const int row = blockIdx.x;
    const int b = row / NCLS, c = row - b * NCLS;
    const float* cq = conf_q + (size_t)b * KPAD;

    for (int i = tid; i < 4096; i += 512) shist[i] = 0;
    if (tid == 0) sh_t = 0;
    __syncthreads();

    // ---- sample phase: 2 scattered keys/thread -> 4096-bin hist ----------
    {
        int q0 = tid * 44, q1 = tid * 44 + 22;
        float lg0 = load_logit(b, c, q0, f0, f1, f2);
        float lg1 = load_logit(b, c, q1, f0, f1, f2);
        unsigned fk0 = __float_as_uint(cq[q0] * sig_fast(lg0)) >> 16;
        unsigned fk1 = __float_as_uint(cq[q1] * sig_fast(lg1)) >> 16;
        atomicAdd(&shist[fk0 >> 4], 1u);
        atomicAdd(&shist[fk1 >> 4], 1u);
    }
    __syncthreads();

    // pick t = bin of the SAMPLE_K-th largest sample (suffix scan, tid<256)
    {
        const int lane = tid & 63;
        unsigned own = 0;
        if (tid < 256) {
            #pragma unroll
            for (int u = 0; u < 16; ++u) own += shist[tid * 16 + u];
        }
        unsigned acc = own;
        #pragma unroll
        for (int d = 1; d < 64; d <<= 1) {
            unsigned vv = __shfl_down(acc, d, 64);
            if (lane + d < 64) acc += vv;
        }
        if (tid < 256 && lane == 0) wsum[tid >> 6] = acc;
        __syncthreads();
        if (tid < 256) {
            unsigned tail = 0;
            for (int w2 = (tid >> 6) + 1; w2 < 4; ++w2) tail += wsum[w2];
            unsigned suft = acc + tail;
            unsigned nxt  = suft - own;
            if (suft >= SAMPLE_K && nxt < SAMPLE_K) {
                unsigned above = nxt;
                for (int bb = 15; bb >= 0; --bb) {
                    unsigned cntb = shist[tid * 16 + bb];
                    if (above + cntb >= SAMPLE_K) { sh_t = (unsigned)((tid * 16 + bb) << 4); break; }
                    above += cntb;
                }
            }
        }
        __syncthreads();
    }

    unsigned t = sh_t;
    unsigned cnt = 0;
    for (int attempt = 0; attempt < 6; ++attempt) {
        __syncthreads();
        if (tid == 0) { sh_cnt = 0; sh_cntA = 0; }
        __syncthreads();
        const unsigned tm = (t > 2) ? t - 2 : 0;   // fast-vs-exact margin

        // ---- ONE streaming keygen+collect pass (seam-free mapping) -------
        // layer 2: 5 groups/thread x 8 keys
        #pragma unroll
        for (int k = 0; k < 5; ++k) {
            int g = tid + k * 512;
            if (g < NG2) {
                int q = g * 8;
                int a = q / 5776, s = q - a * 5776;
                const float* fp = f2 + ((size_t)(b * 255 + a * 85 + 5 + c)) * 5776 + s;
                float4 l0 = *(const float4*)fp;
                float4 l1 = *(const float4*)(fp + 4);
                float4 c0 = *(const float4*)(cq + q);
                float4 c1 = *(const float4*)(cq + q + 4);
                float lgv[8] = { l0.x, l0.y, l0.z, l0.w, l1.x, l1.y, l1.z, l1.w };
                float cfv[8] = { c0.x, c0.y, c0.z, c0.w, c1.x, c1.y, c1.z, c1.w };
                #pragma unroll
                for (int j = 0; j < 8; ++j)
                    try_collect(cfv[j], lgv[j], 5415 + 3 * (s + j) + a,
                                tm, t, buf, &sh_cnt, &sh_cntA);
            }
        }
        // layer 1 (float4/plane) + layer 0 (scalar/plane), tid<361
        if (tid < 361) {
            #pragma unroll
            for (int p = 0; p < 3; ++p) {
                int q1 = Q_L1 + p * 1444 + 4 * tid;
                const float* fp = f1 + ((size_t)(b * 255 + p * 85 + 5 + c)) * 1444 + 4 * tid;
                float4 lg = *(const float4*)fp;
                float4 cf = *(const float4*)(cq + q1);
                float lgv[4] = { lg.x, lg.y, lg.z, lg.w };
                float cfv[4] = { cf.x, cf.y, cf.z, cf.w };
                #pragma unroll
                for (int j = 0; j < 4; ++j)
                    try_collect(cfv[j], lgv[j], 1083 + 3 * (4 * tid + j) + p,
                                tm, t, buf, &sh_cnt, &sh_cntA);

                float g0  = f0[((size_t)(b * 255 + p * 85 + 5 + c)) * 361 + tid];
                float cf0 = cq[Q_L0 + p * 361 + tid];
                try_collect(cf0, g0, 3 * tid + p, tm, t, buf, &sh_cnt, &sh_cntA);
            }
        }
        __syncthreads();
        unsigned cntA = sh_cntA; cnt = sh_cnt;
        if (cntA >= TOPK && cnt <= BUFCAP) break;  // exactness certified
        if (cntA < TOPK) t = (t > 128) ? t - 128 : 0;
        else             t += 128;
    }
    const int M = (int)min(cnt, (unsigned)BUFCAP);

    // defensive init (only matters on pathological exhausted-retry rows)
    if (tid < TOPK) {
        sb_s[tid] = -1.0f;
        sb_y1[tid] = 0.f; sb_x1[tid] = 0.f; sb_y2[tid] = 0.f; sb_x2[tid] = 0.f;
    }
    __syncthreads();

    // rank-by-count (exact score bits + ~n tie-break; keys unique)
    for (int i = tid; i < M; i += 512) {
        unsigned long long mykey = buf[i];
        int rank = 0;
        for (int j = 0; j < M; ++j) rank += (buf[j] > mykey);   // LDS broadcast
        if (rank < TOPK) {
            int n = (int)(~(unsigned)mykey);
            float4 bx = boxes[(size_t)b * NTOT + n];
            sb_y1[rank] = bx.x; sb_x1[rank] = bx.y;
            sb_y2[rank] = bx.z; sb_x2[rank] = bx.w;
            sb_s[rank]  = __uint_as_float((unsigned)(mykey >> 32));
            top_b[(size_t)row * TOPK + rank] = bx;
        }
    }
    __syncthreads();

    // fused greedy NMS on wave 0 (reference-exact op order)
    if (tid < 64) {
        const int j0 = tid, j1 = tid + 64;
        const bool v1 = (j1 < TOPK);
        float y10 = sb_y1[j0], x10 = sb_x1[j0], y20 = sb_y2[j0], x20 = sb_x2[j0];
        float s0 = sb_s[j0];
        float y11 = v1 ? sb_y1[j1] : 0.f, x11 = v1 ? sb_x1[j1] : 0.f;
        float y21 = v1 ? sb_y2[j1] : 0.f, x21 = v1 ? sb_x2[j1] : 0.f;
        float s1 = v1 ? sb_s[j1] : -1.0f;
        float ar0 = fmaxf(y20 - y10, 0.f) * fmaxf(x20 - x10, 0.f);
        float ar1 = fmaxf(y21 - y11, 0.f) * fmaxf(x21 - x11, 0.f);
        int sup0 = 0, sup1 = 0;
        for (int i = 0; i < TOPK; ++i) {
            float yi1 = sb_y1[i], xi1 = sb_x1[i], yi2 = sb_y2[i], xi2 = sb_x2[i];
            float si = sb_s[i];
            int supi = (i < 64) ? __shfl(sup0, i, 64) : __shfl(sup1, i - 64, 64);
            bool keep_i = (si >= SCORE_THR) && (supi == 0);
            if (keep_i) {
                float ari = fmaxf(yi2 - yi1, 0.f) * fmaxf(xi2 - xi1, 0.f);
                if (j0 > i) {
                    float ty1 = fmaxf(yi1, y10), tx1 = fmaxf(xi1, x10);
                    float ty2 = fminf(yi2, y20), tx2 = fminf(xi2, x20);
                    float inter = fmaxf(ty2 - ty1, 0.f) * fmaxf(tx2 - tx1, 0.f);
                    float iou = inter / (ari + ar0 - inter + 1e-9f);
                    if (iou > NMS_THR) sup0 = 1;
                }
                if (v1 && j1 > i) {
                    float ty1 = fmaxf(yi1, y11), tx1 = fmaxf(xi1, x11);
                    float ty2 = fminf(yi2, y21), tx2 = fminf(xi2, x21);
                    float inter = fmaxf(ty2 - ty1, 0.f) * fmaxf(tx2 - tx1, 0.f);
                    float iou = inter / (ari + ar1 - inter + 1e-9f);
                    if (iou > NMS_THR) sup1 = 1;
                }
            }
        }
        cand[(size_t)row * TOPK + j0] = (s0 >= SCORE_THR && sup0 == 0) ? s0 : -1.0f;
        if (v1)
            cand[(size_t)row * TOPK + j1] = (s1 >= SCORE_THR && sup1 == 0) ? s1 : -1.0f;
    }
}

// -------------------------- K3: per-image top-100 -------------------------
__global__ __launch_bounds__(256) void k_final(
    const float* __restrict__ cand, const float4* __restrict__ top_b,
    float* __restrict__ out) {
    __shared__ float cs[8000];                     // 32 KB
    __shared__ unsigned int hist[4096];            // 16 KB
    __shared__ unsigned long long buf[512];
    __shared__ unsigned int suf[256];
    __shared__ unsigned int sh_kp, sh_p1, sh_above1, sh_p2, sh_above2, sh_cnt;

    const int tid = threadIdx.x, b = blockIdx.x;
    if (tid == 0) { sh_kp = 0; sh_cnt = 0; }
    for (int i = tid; i < 4096; i += 256) hist[i] = 0;
    __syncthreads();

    unsigned lk = 0;
    for (int i = tid; i < 8000; i += 256) {
        float v = cand[b * 8000 + i];
        cs[i] = v;
        if (v > -0.5f) lk++;
    }
    atomicAdd(&sh_kp, lk);
    __syncthreads();
    unsigned Kp = sh_kp;

    if (Kp >= TOPK) {
        for (int i = tid; i < 8000; i += 256)
            if (cs[i] > -0.5f) atomicAdd(&hist[__float_as_uint(cs[i]) >> 19], 1u);
        __syncthreads();
        find_pivot(hist, 2048, TOPK, suf, &sh_p1, &sh_above1);
        unsigned p1 = sh_p1, above1 = sh_above1;
        for (int i = tid; i < 4096; i += 256) hist[i] = 0;
        __syncthreads();
        for (int i = tid; i < 8000; i += 256) {
            float v = cs[i];
            if (v > -0.5f) {
                unsigned bits = __float_as_uint(v);
                if ((bits >> 19) == p1) atomicAdd(&hist[(bits >> 7) & 0xFFFu], 1u);
            }
        }
        __syncthreads();
        find_pivot(hist, 4096, TOPK - above1, suf, &sh_p2, &sh_above2);
        unsigned p2 = sh_p2;
        for (int i = tid; i < 8000; i += 256) {
            float v = cs[i];
            if (v > -0.5f) {
                unsigned bits = __float_as_uint(v);
                unsigned b1 = bits >> 19;
                if (b1 > p1 || (b1 == p1 && ((bits >> 7) & 0xFFFu) >= p2)) {
                    unsigned slot = atomicAdd(&sh_cnt, 1u);
                    if (slot < 512)
                        buf[slot] = (((unsigned long long)bits) << 32) | (unsigned)(~i);
                }
            }
        }
    } else {
        // < 100 kept: all kept + smallest flat indices among exact -1.0 ties
        for (int i = tid; i < 8000; i += 256) {
            float v = cs[i];
            if (v > -0.5f) {
                unsigned slot = atomicAdd(&sh_cnt, 1u);
                buf[slot] = (((unsigned long long)__float_as_uint(v)) << 32) | (unsigned)(~i);
            }
        }
        __syncthreads();
        if (tid == 0) {
            unsigned need = TOPK - Kp, got = 0;
            for (int i = 0; i < 8000 && got < need; ++i)
                if (cs[i] <= -0.5f) { buf[Kp + got] = (unsigned)(~i); got++; }
        }
    }
    __syncthreads();

    // rank-by-count epilogue (keys unique via distinct ~i)
    const int M2 = (Kp >= TOPK) ? (int)min(sh_cnt, 512u) : (int)TOPK;
    for (int i = tid; i < M2; i += 256) {
        unsigned long long key = buf[i];
        int rank = 0;
        for (int j = 0; j < M2; ++j) rank += (buf[j] > key);
        if (rank < TOPK) {
            int fi = (int)(~(unsigned)key);
            int c = fi / TOPK; int kk = fi - c * TOPK;
            float4 bb = top_b[((size_t)b * NCLS + c) * TOPK + kk];
            int base = (b * TOPK + rank) * 6;
            out[base + 0] = bb.x; out[base + 1] = bb.y;
            out[base + 2] = bb.z; out[base + 3] = bb.w;
            out[base + 4] = cs[fi]; out[base + 5] = (float)c;
        }
    }
}

// ---------------------------------------------------------------------------
extern "C" void kernel_launch(void* const* d_in, const int* in_sizes, int n_in,
                              void* d_out, int out_size, void* d_ws, size_t ws_size,
                              hipStream_t stream) {
    (void)n_in; (void)out_size; (void)ws_size;
    const float* f0      = (const float*)d_in[0];
    const float* f1      = (const float*)d_in[1];
    const float* f2      = (const float*)d_in[2];
    const float* anchors = (const float*)d_in[3];
    const float* imshape = (const float*)d_in[4];
    const int B = in_sizes[0] / (255 * 19 * 19);

    char* ws = (char*)d_ws;
    size_t o = 0;
    float4* boxes  = (float4*)(ws + o); o += (size_t)B * NTOT * sizeof(float4);
    float*  conf_q = (float*)(ws + o);  o += (size_t)B * KPAD * sizeof(float);
    float4* top_b  = (float4*)(ws + o); o += (size_t)B * NCLS * TOPK * sizeof(float4);
    float*  cand   = (float*)(ws + o);  o += (size_t)B * NCLS * TOPK * sizeof(float);
    float*  out    = (float*)d_out;

    const int total = B * NTOT;
    k_decode<<<(total + 255) / 256, 256, 0, stream>>>(f0, f1, f2, anchors, imshape,
                                                      boxes, conf_q, total);
    k_topk<<<B * NCLS, 512, 0, stream>>>(f0, f1, f2, conf_q, boxes,
                                         top_b, cand);
    k_final<<<B, 256, 0, stream>>>(cand, top_b, out);
}

// Round 8
// 337.262 us; speedup vs baseline: 1.4453x; 1.4453x over previous
//
#include <hip/hip_runtime.h>

// ---------------------------------------------------------------------------
// YOLOv3 post-processing pipeline (round 14):
//   K1 decode : boxes + conf_q (proven, verbatim)
//   K2 topk   : sample-threshold single-scan select, SPILL-FIXED.
//               r13's 172MB scratch spill was the compiler hoisting the
//               loop-invariant loads out of the retry loop and keeping 40
//               float4s live across it. Fix: addresses offset by attempt*opq
//               (opq = opaque zero) -> loads stay in-loop, no hoist, and the
//               retry is never taken in practice.
//               - 4096 exact-score samples -> 4096-bin hist -> threshold
//                 (edge of the 32nd-largest sample's bin)
//               - ONE streaming pass: exact sig everywhere (one metric, no
//                 margin), collect score >= tm into LDS buf (cap 2048)
//               - certificate: 100 <= cnt <= 2048 proves exact top-100 subset
//                 (else bounded retry: lower 2 binades / raise 1 bin)
//               - mini-pivot (4096-bin) over M collected -> ~100-160
//                 survivors -> rank-by-count over survivors only
//               Removes: 29M-LDS-atomic full histogram, the second full
//               pass, collect's scattered gathers, the big rank.
//   K3 final  : per-image top-100 of 8000 (verbatim)
// ---------------------------------------------------------------------------

#define NTOT   22743      // 3*(19^2 + 38^2 + 76^2)
#define NCLS   80
#define TOPK   100
#define KPAD   22752      // row stride for conf_q (16B aligned, 8-div)
#define NG2    2166       // 8-key groups in layer 2 (17328 keys)
#define Q_L1   17328
#define Q_L0   21660
#define NSAMP  4096
#define SAMPLE_K 32       // E[collected] ~ 32/4096*22743 ~ 180 (+bin slack)
#define BUFCAP 2048
#define SCORE_THR 0.2f
#define NMS_THR   0.3f

__device__ __forceinline__ float sig_exact(float x) {
    return 1.0f / (1.0f + expf(-x));          // precise OCML expf + IEEE div
}

// -------------------------- K1: decode (plane-major) ----------------------
__global__ __launch_bounds__(256) void k_decode(
    const float* __restrict__ f0, const float* __restrict__ f1,
    const float* __restrict__ f2, const float* __restrict__ anchors,
    const float* __restrict__ imshape, float4* __restrict__ boxes,
    float* __restrict__ conf_q, int total) {
    int gid = blockIdx.x * 256 + threadIdx.x;
    if (gid >= total) return;
    int b = gid / NTOT; int p = gid - b * NTOT;

    const float* f; int ghw, gw, l, off, a, s;
    if (p < 1083)      { f=f0; off=0;    ghw=361;  gw=19; l=0; int r=p;      a=r/361;  s=r-a*361;  }
    else if (p < 5415) { f=f1; off=1083; ghw=1444; gw=38; l=1; int r=p-1083; a=r/1444; s=r-a*1444; }
    else               { f=f2; off=5415; ghw=5776; gw=76; l=2; int r=p-5415; a=r/5776; s=r-a*5776; }
    int y = s / gw, x = s - y * gw;

    const float* q = f + ((size_t)(b * 255 + a * 85) * ghw + s);
    float tx = q[0], ty = q[ghw], tw = q[2*ghw], th = q[3*ghw], tc = q[4*ghw];

    int arow = (2 - l) * 3 + a;
    float aw = anchors[arow * 2], ah = anchors[arow * 2 + 1];
    float imh = imshape[0], imw = imshape[1];
    float gf = (float)gw;                       // gh == gw for all layers

    float bxx = (sig_exact(tx) + (float)x) / gf;
    float bxy = (sig_exact(ty) + (float)y) / gf;
    float bw  = expf(tw) * aw / 608.0f;
    float bh  = expf(th) * ah / 608.0f;

    float r  = fminf(608.0f / imh, 608.0f / imw);
    float nh = rintf(imh * r), nw = rintf(imw * r);
    float offy = (608.0f - nh) / 2.0f / 608.0f;
    float offx = (608.0f - nw) / 2.0f / 608.0f;
    float scy = 608.0f / nh, scx = 608.0f / nw;

    float cy = (bxy - offy) * scy;
    float cx = (bxx - offx) * scx;
    float hh = bh * scy, ww = bw * scx;

    int n = off + 3 * s + a;                    // anchor-major output index
    boxes[(size_t)b * NTOT + n] =
        make_float4((cy - hh / 2.0f) * imh, (cx - ww / 2.0f) * imw,
                    (cy + hh / 2.0f) * imh, (cx + ww / 2.0f) * imw);
    int qi = (l == 2) ? (a * 5776 + s)
           : (l == 1) ? (Q_L1 + a * 1444 + s)
                      : (Q_L0 + a * 361 + s);
    conf_q[(size_t)b * KPAD + qi] = sig_exact(tc);
}

// ------------------ shared select helpers ---------------------------------
// 256-thread two-level pivot (k_final only)
__device__ void find_pivot(unsigned* hist, int H, unsigned target,
                           unsigned* suf, unsigned* sh_p, unsigned* sh_above) {
    const int tid = threadIdx.x;
    const int per = H >> 8;
    if (tid < 256) {
        unsigned acc = 0;
        for (int u = 0; u < per; ++u) acc += hist[tid * per + u];
        suf[tid] = acc;
    }
    __syncthreads();
    for (int off = 1; off < 256; off <<= 1) {
        unsigned v = 0;
        if (tid < 256) v = (tid + off < 256) ? suf[tid + off] : 0u;
        __syncthreads();
        if (tid < 256) suf[tid] += v;
        __syncthreads();
    }
    if (tid < 256) {
        unsigned mysuf = suf[tid];
        unsigned nxt = (tid == 255) ? 0u : suf[tid + 1];
        if (mysuf >= target && nxt < target) {
            unsigned above = nxt;
            for (int h = tid * per + per - 1; h >= tid * per; --h) {
                unsigned c2 = above + hist[h];
                if (c2 >= target) { *sh_p = (unsigned)h; *sh_above = above; break; }
                above = c2;
            }
        }
    }
    __syncthreads();
}

// 512-thread suffix pick over a 4096-bin hist: bin where top-suffix crosses target
__device__ __forceinline__ void suffix_pick512(
    unsigned* hist, unsigned target, unsigned* wsum8, unsigned* sh_bin) {
    const int tid = threadIdx.x, lane = tid & 63, w = tid >> 6;
    unsigned own = 0;
    #pragma unroll
    for (int u = 0; u < 8; ++u) own += hist[tid * 8 + u];
    unsigned acc = own;
    #pragma unroll
    for (int d = 1; d < 64; d <<= 1) {
        unsigned v = __shfl_down(acc, d, 64);
        if (lane + d < 64) acc += v;
    }
    if (lane == 0) wsum8[w] = acc;
    __syncthreads();
    unsigned tail = 0;
    for (int w2 = w + 1; w2 < 8; ++w2) tail += wsum8[w2];
    unsigned suft = acc + tail, nxt = suft - own;
    if (suft >= target && nxt < target) {
        unsigned above = nxt;
        for (int bb = 7; bb >= 0; --bb) {
            unsigned cb = hist[tid * 8 + bb];
            if (above + cb >= target) { *sh_bin = (unsigned)(tid * 8 + bb); break; }
            above += cb;
        }
    }
    __syncthreads();
}

// q -> logit address decode (sample phase only)
__device__ __forceinline__ float load_logit(int b, int c, int q,
    const float* __restrict__ f0, const float* __restrict__ f1,
    const float* __restrict__ f2) {
    int a, s, ghw; const float* f;
    if (q < Q_L1)      { f = f2; ghw = 5776; a = q / 5776;  s = q - a * 5776; }
    else if (q < Q_L0) { f = f1; ghw = 1444; int r = q - Q_L1; a = r / 1444; s = r - a * 1444; }
    else               { f = f0; ghw = 361;  int r = q - Q_L0; a = r / 361;  s = r - a * 361; }
    return f[((size_t)(b * 255 + a * 85 + 5 + c)) * ghw + s];
}

__device__ __forceinline__ void push_ge(
    float cf, float lg, int n, float tm,
    unsigned long long* buf, unsigned* sh_cnt) {
    float sce = cf * sig_exact(lg);
    if (sce >= tm) {
        unsigned slot = atomicAdd(sh_cnt, 1u);
        if (slot < BUFCAP)
            buf[slot] = (((unsigned long long)__float_as_uint(sce)) << 32)
                        | (unsigned)(~n);
    }
}

// -------------------------- K2: sample+scan topk + NMS --------------------
__global__ __launch_bounds__(512, 4) void k_topk(
    const float* __restrict__ f0, const float* __restrict__ f1,
    const float* __restrict__ f2, const float* __restrict__ conf_q,
    const float4* __restrict__ boxes, float4* __restrict__ top_b,
    float* __restrict__ cand) {
    __shared__ unsigned int shist[4096];           // 16 KB
    __shared__ unsigned long long buf[BUFCAP];     // 16 KB
    __shared__ unsigned long long buf2[512];       // 4 KB survivors
    __shared__ unsigned int wsum8[8];
    __shared__ float sb_y1[TOPK], sb_x1[TOPK], sb_y2[TOPK], sb_x2[TOPK], sb_s[TOPK];
    __shared__ unsigned int sh_t, sh_b2, sh_cnt, sh_cnt2;

    const int tid = threadIdx.x;
    const int row = blockIdx.x;
    const int b = row / NCLS, c = row - b * NCLS;
    const float* cq = conf_q + (size_t)b * KPAD;

    for (int i = tid; i < 4096; i += 512) shist[i] = 0;
    if (tid == 0) { sh_t = 0; sh_b2 = 0; }
    __syncthreads();

    // ---- sample: 8 exact scores/thread (fixed strided positions) ---------
    #pragma unroll
    for (int k = 0; k < 8; ++k) {
        int i = k * 512 + tid;
        int qq = (int)(((long long)i * NTOT) >> 12);      // [0, 22737]
        float lg = load_logit(b, c, qq, f0, f1, f2);
        float sce = cq[qq] * sig_exact(lg);
        atomicAdd(&shist[__float_as_uint(sce) >> 18], 1u);
    }
    __syncthreads();
    suffix_pick512(shist, SAMPLE_K, wsum8, &sh_t);
    unsigned tmb = sh_t << 18;                     // lower edge of pivot bin

    // ---- streaming collect with certificate + (cold) bounded retry -------
    int opq = 0;
    asm volatile("" : "+v"(opq));                  // opaque zero: anti-hoist
    unsigned cnt = 0;
    for (int attempt = 0;; ++attempt) {
        __syncthreads();
        if (tid == 0) sh_cnt = 0;
        __syncthreads();
        const float tm = __uint_as_float(tmb);
        const int ao = attempt * opq;              // == 0, but loop-variant
        const float* f2v = f2 + ao;
        const float* f1v = f1 + ao;
        const float* f0v = f0 + ao;
        const float* cqv = cq + ao;

        // layer 2: 5 groups/thread x 8 keys, all-vector
        #pragma unroll
        for (int k = 0; k < 5; ++k) {
            int g = tid + k * 512;
            if (g < NG2) {
                int q = g * 8;
                int a = q / 5776, s = q - a * 5776;
                const float* fp = f2v + ((size_t)(b * 255 + a * 85 + 5 + c)) * 5776 + s;
                float4 l0 = *(const float4*)fp;
                float4 l1 = *(const float4*)(fp + 4);
                float4 c0 = *(const float4*)(cqv + q);
                float4 c1 = *(const float4*)(cqv + q + 4);
                push_ge(c0.x, l0.x, 5415 + 3 * (s + 0) + a, tm, buf, &sh_cnt);
                push_ge(c0.y, l0.y, 5415 + 3 * (s + 1) + a, tm, buf, &sh_cnt);
                push_ge(c0.z, l0.z, 5415 + 3 * (s + 2) + a, tm, buf, &sh_cnt);
                push_ge(c0.w, l0.w, 5415 + 3 * (s + 3) + a, tm, buf, &sh_cnt);
                push_ge(c1.x, l1.x, 5415 + 3 * (s + 4) + a, tm, buf, &sh_cnt);
                push_ge(c1.y, l1.y, 5415 + 3 * (s + 5) + a, tm, buf, &sh_cnt);
                push_ge(c1.z, l1.z, 5415 + 3 * (s + 6) + a, tm, buf, &sh_cnt);
                push_ge(c1.w, l1.w, 5415 + 3 * (s + 7) + a, tm, buf, &sh_cnt);
            }
        }
        // layer 1 (one float4/plane) + layer 0 (one scalar/plane), tid<361
        if (tid < 361) {
            #pragma unroll
            for (int p = 0; p < 3; ++p) {
                int q1 = Q_L1 + p * 1444 + 4 * tid;
                const float* fp = f1v + ((size_t)(b * 255 + p * 85 + 5 + c)) * 1444 + 4 * tid;
                float4 lg = *(const float4*)fp;
                float4 cf = *(const float4*)(cqv + q1);
                push_ge(cf.x, lg.x, 1083 + 3 * (4 * tid + 0) + p, tm, buf, &sh_cnt);
                push_ge(cf.y, lg.y, 1083 + 3 * (4 * tid + 1) + p, tm, buf, &sh_cnt);
                push_ge(cf.z, lg.z, 1083 + 3 * (4 * tid + 2) + p, tm, buf, &sh_cnt);
                push_ge(cf.w, lg.w, 1083 + 3 * (4 * tid + 3) + p, tm, buf, &sh_cnt);

                float g0  = f0v[((size_t)(b * 255 + p * 85 + 5 + c)) * 361 + tid];
                float cf0 = cqv[Q_L0 + p * 361 + tid];
                push_ge(cf0, g0, 3 * tid + p, tm, buf, &sh_cnt);
            }
        }
        __syncthreads();
        cnt = sh_cnt;
        if ((cnt >= TOPK && cnt <= BUFCAP) || attempt >= 7) break;
        if (cnt < TOPK) tmb = (tmb > (2u << 23)) ? tmb - (2u << 23) : 0u;
        else            tmb += (1u << 18);
    }
    const int M = (int)min(cnt, (unsigned)BUFCAP);

    // ---- mini-pivot over M collected -> survivors in buf2 ----------------
    __syncthreads();
    for (int i = tid; i < 4096; i += 512) shist[i] = 0;
    if (tid == 0) sh_cnt2 = 0;
    __syncthreads();
    for (int i = tid; i < M; i += 512)
        atomicAdd(&shist[(unsigned)(buf[i] >> 32) >> 18], 1u);
    __syncthreads();
    suffix_pick512(shist, TOPK, wsum8, &sh_b2);
    const unsigned thr2 = sh_b2 << 18;
    for (int i = tid; i < M; i += 512) {
        unsigned long long key = buf[i];
        if ((unsigned)(key >> 32) >= thr2) {
            unsigned sl = atomicAdd(&sh_cnt2, 1u);
            if (sl < 512) buf2[sl] = key;
        }
    }
    __syncthreads();
    int M2 = (int)sh_cnt2;
    const unsigned long long* rsrc = buf2; int RM = M2;
    if (M2 > 512) { rsrc = buf; RM = M; }          // impossible-case fallback

    // defensive init (only matters on pathological exhausted-retry rows)
    if (tid < TOPK) {
        sb_s[tid] = -1.0f;
        sb_y1[tid] = 0.f; sb_x1[tid] = 0.f; sb_y2[tid] = 0.f; sb_x2[tid] = 0.f;
    }
    __syncthreads();

    // ---- rank-by-count over survivors only (global rank == survivor rank)
    for (int i = tid; i < RM; i += 512) {
        unsigned long long mykey = rsrc[i];
        int rank = 0;
        for (int j = 0; j < RM; ++j) rank += (rsrc[j] > mykey);
        if (rank < TOPK) {
            int n = (int)(~(unsigned)mykey);
            float4 bx = boxes[(size_t)b * NTOT + n];
            sb_y1[rank] = bx.x; sb_x1[rank] = bx.y;
            sb_y2[rank] = bx.z; sb_x2[rank] = bx.w;
            sb_s[rank]  = __uint_as_float((unsigned)(mykey >> 32));
            top_b[(size_t)row * TOPK + rank] = bx;
        }
    }
    __syncthreads();

    // fused greedy NMS on wave 0 (reference-exact op order)
    if (tid < 64) {
        const int j0 = tid, j1 = tid + 64;
        const bool v1 = (j1 < TOPK);
        float y10 = sb_y1[j0], x10 = sb_x1[j0], y20 = sb_y2[j0], x20 = sb_x2[j0];
        float s0 = sb_s[j0];
        float y11 = v1 ? sb_y1[j1] : 0.f, x11 = v1 ? sb_x1[j1] : 0.f;
        float y21 = v1 ? sb_y2[j1] : 0.f, x21 = v1 ? sb_x2[j1] : 0.f;
        float s1 = v1 ? sb_s[j1] : -1.0f;
        float ar0 = fmaxf(y20 - y10, 0.f) * fmaxf(x20 - x10, 0.f);
        float ar1 = fmaxf(y21 - y11, 0.f) * fmaxf(x21 - x11, 0.f);
        int sup0 = 0, sup1 = 0;
        for (int i = 0; i < TOPK; ++i) {
            float yi1 = sb_y1[i], xi1 = sb_x1[i], yi2 = sb_y2[i], xi2 = sb_x2[i];
            float si = sb_s[i];
            int supi = (i < 64) ? __shfl(sup0, i, 64) : __shfl(sup1, i - 64, 64);
            bool keep_i = (si >= SCORE_THR) && (supi == 0);
            if (keep_i) {
                float ari = fmaxf(yi2 - yi1, 0.f) * fmaxf(xi2 - xi1, 0.f);
                if (j0 > i) {
                    float ty1 = fmaxf(yi1, y10), tx1 = fmaxf(xi1, x10);
                    float ty2 = fminf(yi2, y20), tx2 = fminf(xi2, x20);
                    float inter = fmaxf(ty2 - ty1, 0.f) * fmaxf(tx2 - tx1, 0.f);
                    float iou = inter / (ari + ar0 - inter + 1e-9f);
                    if (iou > NMS_THR) sup0 = 1;
                }
                if (v1 && j1 > i) {
                    float ty1 = fmaxf(yi1, y11), tx1 = fmaxf(xi1, x11);
                    float ty2 = fminf(yi2, y21), tx2 = fminf(xi2, x21);
                    float inter = fmaxf(ty2 - ty1, 0.f) * fmaxf(tx2 - tx1, 0.f);
                    float iou = inter / (ari + ar1 - inter + 1e-9f);
                    if (iou > NMS_THR) sup1 = 1;
                }
            }
        }
        cand[(size_t)row * TOPK + j0] = (s0 >= SCORE_THR && sup0 == 0) ? s0 : -1.0f;
        if (v1)
            cand[(size_t)row * TOPK + j1] = (s1 >= SCORE_THR && sup1 == 0) ? s1 : -1.0f;
    }
}

// -------------------------- K3: per-image top-100 -------------------------
__global__ __launch_bounds__(256) void k_final(
    const float* __restrict__ cand, const float4* __restrict__ top_b,
    float* __restrict__ out) {
    __shared__ float cs[8000];                     // 32 KB
    __shared__ unsigned int hist[4096];            // 16 KB
    __shared__ unsigned long long buf[512];
    __shared__ unsigned int suf[256];
    __shared__ unsigned int sh_kp, sh_p1, sh_above1, sh_p2, sh_above2, sh_cnt;

    const int tid = threadIdx.x, b = blockIdx.x;
    if (tid == 0) { sh_kp = 0; sh_cnt = 0; }
    for (int i = tid; i < 4096; i += 256) hist[i] = 0;
    __syncthreads();

    unsigned lk = 0;
    for (int i = tid; i < 8000; i += 256) {
        float v = cand[b * 8000 + i];
        cs[i] = v;
        if (v > -0.5f) lk++;
    }
    atomicAdd(&sh_kp, lk);
    __syncthreads();
    unsigned Kp = sh_kp;

    if (Kp >= TOPK) {
        for (int i = tid; i < 8000; i += 256)
            if (cs[i] > -0.5f) atomicAdd(&hist[__float_as_uint(cs[i]) >> 19], 1u);
        __syncthreads();
        find_pivot(hist, 2048, TOPK, suf, &sh_p1, &sh_above1);
        unsigned p1 = sh_p1, above1 = sh_above1;
        for (int i = tid; i < 4096; i += 256) hist[i] = 0;
        __syncthreads();
        for (int i = tid; i < 8000; i += 256) {
            float v = cs[i];
            if (v > -0.5f) {
                unsigned bits = __float_as_uint(v);
                if ((bits >> 19) == p1) atomicAdd(&hist[(bits >> 7) & 0xFFFu], 1u);
            }
        }
        __syncthreads();
        find_pivot(hist, 4096, TOPK - above1, suf, &sh_p2, &sh_above2);
        unsigned p2 = sh_p2;
        for (int i = tid; i < 8000; i += 256) {
            float v = cs[i];
            if (v > -0.5f) {
                unsigned bits = __float_as_uint(v);
                unsigned b1 = bits >> 19;
                if (b1 > p1 || (b1 == p1 && ((bits >> 7) & 0xFFFu) >= p2)) {
                    unsigned slot = atomicAdd(&sh_cnt, 1u);
                    if (slot < 512)
                        buf[slot] = (((unsigned long long)bits) << 32) | (unsigned)(~i);
                }
            }
        }
    } else {
        // < 100 kept: all kept + smallest flat indices among exact -1.0 ties
        for (int i = tid; i < 8000; i += 256) {
            float v = cs[i];
            if (v > -0.5f) {
                unsigned slot = atomicAdd(&sh_cnt, 1u);
                buf[slot] = (((unsigned long long)__float_as_uint(v)) << 32) | (unsigned)(~i);
            }
        }
        __syncthreads();
        if (tid == 0) {
            unsigned need = TOPK - Kp, got = 0;
            for (int i = 0; i < 8000 && got < need; ++i)
                if (cs[i] <= -0.5f) { buf[Kp + got] = (unsigned)(~i); got++; }
        }
    }
    __syncthreads();

    // rank-by-count epilogue (keys unique via distinct ~i)
    const int M2 = (Kp >= TOPK) ? (int)min(sh_cnt, 512u) : (int)TOPK;
    for (int i = tid; i < M2; i += 256) {
        unsigned long long key = buf[i];
        int rank = 0;
        for (int j = 0; j < M2; ++j) rank += (buf[j] > key);
        if (rank < TOPK) {
            int fi = (int)(~(unsigned)key);
            int c = fi / TOPK; int kk = fi - c * TOPK;
            float4 bb = top_b[((size_t)b * NCLS + c) * TOPK + kk];
            int base = (b * TOPK + rank) * 6;
            out[base + 0] = bb.x; out[base + 1] = bb.y;
            out[base + 2] = bb.z; out[base + 3] = bb.w;
            out[base + 4] = cs[fi]; out[base + 5] = (float)c;
        }
    }
}

// ---------------------------------------------------------------------------
extern "C" void kernel_launch(void* const* d_in, const int* in_sizes, int n_in,
                              void* d_out, int out_size, void* d_ws, size_t ws_size,
                              hipStream_t stream) {
    (void)n_in; (void)out_size; (void)ws_size;
    const float* f0      = (const float*)d_in[0];
    const float* f1      = (const float*)d_in[1];
    const float* f2      = (const float*)d_in[2];
    const float* anchors = (const float*)d_in[3];
    const float* imshape = (const float*)d_in[4];
    const int B = in_sizes[0] / (255 * 19 * 19);

    char* ws = (char*)d_ws;
    size_t o = 0;
    float4* boxes  = (float4*)(ws + o); o += (size_t)B * NTOT * sizeof(float4);
    float*  conf_q = (float*)(ws + o);  o += (size_t)B * KPAD * sizeof(float);
    float4* top_b  = (float4*)(ws + o); o += (size_t)B * NCLS * TOPK * sizeof(float4);
    float*  cand   = (float*)(ws + o);  o += (size_t)B * NCLS * TOPK * sizeof(float);
    float*  out    = (float*)d_out;

    const int total = B * NTOT;
    k_decode<<<(total + 255) / 256, 256, 0, stream>>>(f0, f1, f2, anchors, imshape,
                                                      boxes, conf_q, total);
    k_topk<<<B * NCLS, 512, 0, stream>>>(f0, f1, f2, conf_q, boxes,
                                         top_b, cand);
    k_final<<<B, 256, 0, stream>>>(cand, top_b, out);
}

// Round 9
// 247.391 us; speedup vs baseline: 1.9703x; 1.3633x over previous
//
#include <hip/hip_runtime.h>

// ---------------------------------------------------------------------------
// YOLOv3 post-processing pipeline (round 15):
//   Base = the proven 262-us round-10 structure (best measured), ONE change:
//   k_topk's histogram atomics are FUSED into the keygen loop (issued while
//   the next iteration's loads are in flight) instead of a separate
//   barrier-delimited pass. Deletes one full 45-key pass + one barrier and
//   overlaps VMEM / VALU(exp,rcp) / DS(atomic) pipes.
//   (r13/r14 sample-threshold line abandoned: two consecutive scratch-spill
//   failures, WRITE_SIZE 172/204 MB.)
//   K1 decode : boxes + conf_q (verbatim)
//   K3 final  : per-image top-100 of 8000 (verbatim)
// ---------------------------------------------------------------------------

#define NTOT   22743      // 3*(19^2 + 38^2 + 76^2)
#define NCLS   80
#define TOPK   100
#define KPAD   22752      // row stride for conf_q (16B aligned, 8-div)
#define NG2    2166       // 8-key groups in layer 2 (17328 keys)
#define Q_L1   17328
#define Q_L0   21660
#define SCORE_THR 0.2f
#define NMS_THR   0.3f

__device__ __forceinline__ float sig_exact(float x) {
    return 1.0f / (1.0f + expf(-x));          // precise OCML expf + IEEE div
}
__device__ __forceinline__ float sig_fast(float x) {
    // monotone surrogate, rel err ~1e-6 << 2^-7 bin margin
    return __builtin_amdgcn_rcpf(1.0f + __expf(-x));
}
__device__ __forceinline__ unsigned pack2(float cfa, float lga, float cfb, float lgb) {
    unsigned ka = __float_as_uint(cfa * sig_fast(lga)) >> 16;
    unsigned kb = __float_as_uint(cfb * sig_fast(lgb)) >> 16;
    return ka | (kb << 16);
}

// -------------------------- K1: decode (plane-major) ----------------------
__global__ __launch_bounds__(256) void k_decode(
    const float* __restrict__ f0, const float* __restrict__ f1,
    const float* __restrict__ f2, const float* __restrict__ anchors,
    const float* __restrict__ imshape, float4* __restrict__ boxes,
    float* __restrict__ conf_q, int total) {
    int gid = blockIdx.x * 256 + threadIdx.x;
    if (gid >= total) return;
    int b = gid / NTOT; int p = gid - b * NTOT;

    const float* f; int ghw, gw, l, off, a, s;
    if (p < 1083)      { f=f0; off=0;    ghw=361;  gw=19; l=0; int r=p;      a=r/361;  s=r-a*361;  }
    else if (p < 5415) { f=f1; off=1083; ghw=1444; gw=38; l=1; int r=p-1083; a=r/1444; s=r-a*1444; }
    else               { f=f2; off=5415; ghw=5776; gw=76; l=2; int r=p-5415; a=r/5776; s=r-a*5776; }
    int y = s / gw, x = s - y * gw;

    const float* q = f + ((size_t)(b * 255 + a * 85) * ghw + s);
    float tx = q[0], ty = q[ghw], tw = q[2*ghw], th = q[3*ghw], tc = q[4*ghw];

    int arow = (2 - l) * 3 + a;
    float aw = anchors[arow * 2], ah = anchors[arow * 2 + 1];
    float imh = imshape[0], imw = imshape[1];
    float gf = (float)gw;                       // gh == gw for all layers

    float bxx = (sig_exact(tx) + (float)x) / gf;
    float bxy = (sig_exact(ty) + (float)y) / gf;
    float bw  = expf(tw) * aw / 608.0f;
    float bh  = expf(th) * ah / 608.0f;

    float r  = fminf(608.0f / imh, 608.0f / imw);
    float nh = rintf(imh * r), nw = rintf(imw * r);
    float offy = (608.0f - nh) / 2.0f / 608.0f;
    float offx = (608.0f - nw) / 2.0f / 608.0f;
    float scy = 608.0f / nh, scx = 608.0f / nw;

    float cy = (bxy - offy) * scy;
    float cx = (bxx - offx) * scx;
    float hh = bh * scy, ww = bw * scx;

    int n = off + 3 * s + a;                    // anchor-major output index
    boxes[(size_t)b * NTOT + n] =
        make_float4((cy - hh / 2.0f) * imh, (cx - ww / 2.0f) * imw,
                    (cy + hh / 2.0f) * imh, (cx + ww / 2.0f) * imw);
    int qi = (l == 2) ? (a * 5776 + s)
           : (l == 1) ? (Q_L1 + a * 1444 + s)
                      : (Q_L0 + a * 361 + s);
    conf_q[(size_t)b * KPAD + qi] = sig_exact(tc);
}

// ------------------ shared select helpers ---------------------------------
__device__ void find_pivot(unsigned* hist, int H, unsigned target,
                           unsigned* suf, unsigned* sh_p, unsigned* sh_above) {
    const int tid = threadIdx.x;
    const int per = H >> 8;
    if (tid < 256) {
        unsigned acc = 0;
        for (int u = 0; u < per; ++u) acc += hist[tid * per + u];
        suf[tid] = acc;
    }
    __syncthreads();
    for (int off = 1; off < 256; off <<= 1) {
        unsigned v = 0;
        if (tid < 256) v = (tid + off < 256) ? suf[tid + off] : 0u;
        __syncthreads();
        if (tid < 256) suf[tid] += v;
        __syncthreads();
    }
    if (tid < 256) {
        unsigned mysuf = suf[tid];
        unsigned nxt = (tid == 255) ? 0u : suf[tid + 1];
        if (mysuf >= target && nxt < target) {
            unsigned above = nxt;
            for (int h = tid * per + per - 1; h >= tid * per; --h) {
                unsigned c2 = above + hist[h];
                if (c2 >= target) { *sh_p = (unsigned)h; *sh_above = above; break; }
                above = c2;
            }
        }
    }
    __syncthreads();
}

// -------------------------- K2: fused topk + NMS --------------------------
__device__ __forceinline__ void collect_cand(
    int b, int c, int q, const float* __restrict__ f0,
    const float* __restrict__ f1, const float* __restrict__ f2,
    const float* __restrict__ conf_q, unsigned long long* buf,
    unsigned* sh_cnt) {
    int a, s, nbase, ghw;
    const float* f;
    if (q < Q_L1)      { a = q / 5776;  s = q - a * 5776;  f = f2; ghw = 5776; nbase = 5415; }
    else if (q < Q_L0) { int r = q - Q_L1; a = r / 1444; s = r - a * 1444; f = f1; ghw = 1444; nbase = 1083; }
    else               { int r = q - Q_L0; a = r / 361;  s = r - a * 361;  f = f0; ghw = 361;  nbase = 0;    }
    float t  = f[((size_t)(b * 255 + a * 85 + 5 + c)) * ghw + s];
    float cf = conf_q[(size_t)b * KPAD + q];
    float sce = cf * sig_exact(t);
    int n = nbase + 3 * s + a;
    unsigned slot = atomicAdd(sh_cnt, 1u);
    if (slot < 512)
        buf[slot] = (((unsigned long long)__float_as_uint(sce)) << 32)
                    | (unsigned)(~n);
}

__device__ __forceinline__ void hist8(unsigned* histp, unsigned w0, unsigned w1,
                                      unsigned w2, unsigned w3) {
    unsigned ks[8] = { w0 & 0xFFFFu, w0 >> 16, w1 & 0xFFFFu, w1 >> 16,
                       w2 & 0xFFFFu, w2 >> 16, w3 & 0xFFFFu, w3 >> 16 };
    #pragma unroll
    for (int j = 0; j < 8; ++j)
        atomicAdd(&histp[ks[j] >> 2], 1u << (((ks[j] >> 1) & 1u) * 16));
}

__global__ __launch_bounds__(512, 4) void k_topk(
    const float* __restrict__ f0, const float* __restrict__ f1,
    const float* __restrict__ f2, const float* __restrict__ conf_q,
    const float4* __restrict__ boxes, float4* __restrict__ top_b,
    float* __restrict__ cand) {
    __shared__ unsigned int histp[4096];           // packed u16x2: 8192 bins, 16 KB
    __shared__ unsigned long long buf[512];        // 4 KB
    __shared__ unsigned int wsum[4];
    __shared__ float sb_y1[TOPK], sb_x1[TOPK], sb_y2[TOPK], sb_x2[TOPK], sb_s[TOPK];
    __shared__ unsigned int sh_p, sh_cnt;

    const int tid = threadIdx.x;
    const int row = blockIdx.x;
    const int b = row / NCLS, c = row - b * NCLS;
    const float* cq = conf_q + (size_t)b * KPAD;

    for (int i = tid; i < 4096; i += 512) histp[i] = 0;
    if (tid == 0) sh_cnt = 0;
    __syncthreads();                               // hist zeroed BEFORE keygen

    // ---- keygen + histogram FUSED: atomic issued per packed word while
    //      next iteration's loads are in flight (VMEM || VALU || DS overlap)
    // layer 2: 5 groups/thread
    uint4 v[5];
    bool  val[5];
    #pragma unroll
    for (int k = 0; k < 5; ++k) {
        int g = tid + k * 512;
        val[k] = (g < NG2);
        if (val[k]) {
            int q = g * 8;
            int a = q / 5776, s = q - a * 5776;
            const float* fp = f2 + ((size_t)(b * 255 + a * 85 + 5 + c)) * 5776 + s;
            float4 l0 = *(const float4*)fp;
            float4 l1 = *(const float4*)(fp + 4);
            float4 c0 = *(const float4*)(cq + q);
            float4 c1 = *(const float4*)(cq + q + 4);
            v[k].x = pack2(c0.x, l0.x, c0.y, l0.y);
            v[k].y = pack2(c0.z, l0.z, c0.w, l0.w);
            v[k].z = pack2(c1.x, l1.x, c1.y, l1.y);
            v[k].w = pack2(c1.z, l1.z, c1.w, l1.w);
            hist8(histp, v[k].x, v[k].y, v[k].z, v[k].w);
        } else v[k] = make_uint4(0, 0, 0, 0);
    }

    // layer 1: 3 whole planes, one float4/thread (tid<361), fused atomics
    const bool lv = (tid < 361);
    unsigned k1p[6];
    if (lv) {
        #pragma unroll
        for (int p = 0; p < 3; ++p) {
            const float* fp = f1 + ((size_t)(b * 255 + p * 85 + 5 + c)) * 1444 + 4 * tid;
            float4 lg = *(const float4*)fp;
            float4 cf = *(const float4*)(cq + Q_L1 + p * 1444 + 4 * tid);
            unsigned w0 = pack2(cf.x, lg.x, cf.y, lg.y);
            unsigned w1 = pack2(cf.z, lg.z, cf.w, lg.w);
            k1p[2*p] = w0; k1p[2*p+1] = w1;
            unsigned ks[4] = { w0 & 0xFFFFu, w0 >> 16, w1 & 0xFFFFu, w1 >> 16 };
            #pragma unroll
            for (int j = 0; j < 4; ++j)
                atomicAdd(&histp[ks[j] >> 2], 1u << (((ks[j] >> 1) & 1u) * 16));
        }
    }

    // layer 0: 3 planes, one scalar/thread (tid<361), fused atomics
    unsigned k0[3];
    if (lv) {
        #pragma unroll
        for (int p = 0; p < 3; ++p) {
            float g0 = f0[((size_t)(b * 255 + p * 85 + 5 + c)) * 361 + tid];
            float c0 = cq[Q_L0 + p * 361 + tid];
            k0[p] = __float_as_uint(c0 * sig_fast(g0)) >> 16;
            atomicAdd(&histp[k0[p] >> 2], 1u << (((k0[p] >> 1) & 1u) * 16));
        }
    }
    __syncthreads();

    // pivot: group t (tid<256) covers bins [t*32,t*32+32) = words [t*16,t*16+16)
    {
        const int lane = tid & 63;
        unsigned own = 0;
        if (tid < 256) {
            #pragma unroll
            for (int u = 0; u < 16; ++u) {
                unsigned w = histp[tid * 16 + u];
                own += (w & 0xFFFFu) + (w >> 16);
            }
        }
        unsigned acc = own;                        // wave-level suffix scan
        #pragma unroll
        for (int d = 1; d < 64; d <<= 1) {
            unsigned vv = __shfl_down(acc, d, 64);
            if (lane + d < 64) acc += vv;
        }
        if (tid < 256 && lane == 0) wsum[tid >> 6] = acc;
        __syncthreads();
        if (tid < 256) {
            unsigned tail = 0;
            for (int w2 = (tid >> 6) + 1; w2 < 4; ++w2) tail += wsum[w2];
            unsigned suft = acc + tail;            // suffix incl own group
            unsigned nxt  = suft - own;            // suffix of groups above
            if (suft >= TOPK && nxt < TOPK) {
                unsigned above = nxt;
                for (int bb = 31; bb >= 0; --bb) {
                    unsigned w = histp[tid * 16 + (bb >> 1)];
                    unsigned cnt = (bb & 1) ? (w >> 16) : (w & 0xFFFFu);
                    if (above + cnt >= TOPK) { sh_p = (unsigned)(tid * 32 + bb); break; }
                    above += cnt;
                }
            }
        }
        __syncthreads();
    }
    const unsigned kthr = sh_p > 0 ? ((sh_p - 1) << 1) : 0u;  // one-bin margin

    // pass 2: collect candidates FROM REGISTERS, exact rescore
    #pragma unroll
    for (int k = 0; k < 5; ++k) if (val[k]) {
        unsigned ks[8] = { v[k].x & 0xFFFFu, v[k].x >> 16, v[k].y & 0xFFFFu, v[k].y >> 16,
                           v[k].z & 0xFFFFu, v[k].z >> 16, v[k].w & 0xFFFFu, v[k].w >> 16 };
        #pragma unroll
        for (int j = 0; j < 8; ++j)
            if (ks[j] >= kthr)
                collect_cand(b, c, (tid + k * 512) * 8 + j, f0, f1, f2, conf_q, buf, &sh_cnt);
    }
    if (lv) {
        #pragma unroll
        for (int p = 0; p < 3; ++p) {
            unsigned ks[4] = { k1p[2*p] & 0xFFFFu, k1p[2*p] >> 16,
                               k1p[2*p+1] & 0xFFFFu, k1p[2*p+1] >> 16 };
            #pragma unroll
            for (int j = 0; j < 4; ++j)
                if (ks[j] >= kthr)
                    collect_cand(b, c, Q_L1 + p * 1444 + 4 * tid + j, f0, f1, f2, conf_q, buf, &sh_cnt);
            if (k0[p] >= kthr)
                collect_cand(b, c, Q_L0 + p * 361 + tid, f0, f1, f2, conf_q, buf, &sh_cnt);
        }
    }
    __syncthreads();

    // rank-by-count (keys unique: (score_bits, ~n)); M >= 100 by construction
    const int M = (int)min(sh_cnt, 512u);
    if (tid < M) {
        unsigned long long mykey = buf[tid];
        int rank = 0;
        for (int j = 0; j < M; ++j) rank += (buf[j] > mykey);   // LDS broadcast
        if (rank < TOPK) {
            int n = (int)(~(unsigned)mykey);
            float4 bx = boxes[(size_t)b * NTOT + n];
            sb_y1[rank] = bx.x; sb_x1[rank] = bx.y;
            sb_y2[rank] = bx.z; sb_x2[rank] = bx.w;
            sb_s[rank]  = __uint_as_float((unsigned)(mykey >> 32));
            top_b[(size_t)row * TOPK + rank] = bx;
        }
    }
    __syncthreads();

    // fused greedy NMS on wave 0 (reference-exact op order)
    if (tid < 64) {
        const int j0 = tid, j1 = tid + 64;
        const bool v1 = (j1 < TOPK);
        float y10 = sb_y1[j0], x10 = sb_x1[j0], y20 = sb_y2[j0], x20 = sb_x2[j0];
        float s0 = sb_s[j0];
        float y11 = v1 ? sb_y1[j1] : 0.f, x11 = v1 ? sb_x1[j1] : 0.f;
        float y21 = v1 ? sb_y2[j1] : 0.f, x21 = v1 ? sb_x2[j1] : 0.f;
        float s1 = v1 ? sb_s[j1] : -1.0f;
        float ar0 = fmaxf(y20 - y10, 0.f) * fmaxf(x20 - x10, 0.f);
        float ar1 = fmaxf(y21 - y11, 0.f) * fmaxf(x21 - x11, 0.f);
        int sup0 = 0, sup1 = 0;
        for (int i = 0; i < TOPK; ++i) {
            float yi1 = sb_y1[i], xi1 = sb_x1[i], yi2 = sb_y2[i], xi2 = sb_x2[i];
            float si = sb_s[i];
            int supi = (i < 64) ? __shfl(sup0, i, 64) : __shfl(sup1, i - 64, 64);
            bool keep_i = (si >= SCORE_THR) && (supi == 0);
            if (keep_i) {
                float ari = fmaxf(yi2 - yi1, 0.f) * fmaxf(xi2 - xi1, 0.f);
                if (j0 > i) {
                    float ty1 = fmaxf(yi1, y10), tx1 = fmaxf(xi1, x10);
                    float ty2 = fminf(yi2, y20), tx2 = fminf(xi2, x20);
                    float inter = fmaxf(ty2 - ty1, 0.f) * fmaxf(tx2 - tx1, 0.f);
                    float iou = inter / (ari + ar0 - inter + 1e-9f);
                    if (iou > NMS_THR) sup0 = 1;
                }
                if (v1 && j1 > i) {
                    float ty1 = fmaxf(yi1, y11), tx1 = fmaxf(xi1, x11);
                    float ty2 = fminf(yi2, y21), tx2 = fminf(xi2, x21);
                    float inter = fmaxf(ty2 - ty1, 0.f) * fmaxf(tx2 - tx1, 0.f);
                    float iou = inter / (ari + ar1 - inter + 1e-9f);
                    if (iou > NMS_THR) sup1 = 1;
                }
            }
        }
        cand[(size_t)row * TOPK + j0] = (s0 >= SCORE_THR && sup0 == 0) ? s0 : -1.0f;
        if (v1)
            cand[(size_t)row * TOPK + j1] = (s1 >= SCORE_THR && sup1 == 0) ? s1 : -1.0f;
    }
}

// -------------------------- K3: per-image top-100 -------------------------
__global__ __launch_bounds__(256) void k_final(
    const float* __restrict__ cand, const float4* __restrict__ top_b,
    float* __restrict__ out) {
    __shared__ float cs[8000];                     // 32 KB
    __shared__ unsigned int hist[4096];            // 16 KB
    __shared__ unsigned long long buf[512];
    __shared__ unsigned int suf[256];
    __shared__ unsigned int sh_kp, sh_p1, sh_above1, sh_p2, sh_above2, sh_cnt;

    const int tid = threadIdx.x, b = blockIdx.x;
    if (tid == 0) { sh_kp = 0; sh_cnt = 0; }
    for (int i = tid; i < 4096; i += 256) hist[i] = 0;
    __syncthreads();

    unsigned lk = 0;
    for (int i = tid; i < 8000; i += 256) {
        float v = cand[b * 8000 + i];
        cs[i] = v;
        if (v > -0.5f) lk++;
    }
    atomicAdd(&sh_kp, lk);
    __syncthreads();
    unsigned Kp = sh_kp;

    if (Kp >= TOPK) {
        for (int i = tid; i < 8000; i += 256)
            if (cs[i] > -0.5f) atomicAdd(&hist[__float_as_uint(cs[i]) >> 19], 1u);
        __syncthreads();
        find_pivot(hist, 2048, TOPK, suf, &sh_p1, &sh_above1);
        unsigned p1 = sh_p1, above1 = sh_above1;
        for (int i = tid; i < 4096; i += 256) hist[i] = 0;
        __syncthreads();
        for (int i = tid; i < 8000; i += 256) {
            float v = cs[i];
            if (v > -0.5f) {
                unsigned bits = __float_as_uint(v);
                if ((bits >> 19) == p1) atomicAdd(&hist[(bits >> 7) & 0xFFFu], 1u);
            }
        }
        __syncthreads();
        find_pivot(hist, 4096, TOPK - above1, suf, &sh_p2, &sh_above2);
        unsigned p2 = sh_p2;
        for (int i = tid; i < 8000; i += 256) {
            float v = cs[i];
            if (v > -0.5f) {
                unsigned bits = __float_as_uint(v);
                unsigned b1 = bits >> 19;
                if (b1 > p1 || (b1 == p1 && ((bits >> 7) & 0xFFFu) >= p2)) {
                    unsigned slot = atomicAdd(&sh_cnt, 1u);
                    if (slot < 512)
                        buf[slot] = (((unsigned long long)bits) << 32) | (unsigned)(~i);
                }
            }
        }
    } else {
        // < 100 kept: all kept + smallest flat indices among exact -1.0 ties
        for (int i = tid; i < 8000; i += 256) {
            float v = cs[i];
            if (v > -0.5f) {
                unsigned slot = atomicAdd(&sh_cnt, 1u);
                buf[slot] = (((unsigned long long)__float_as_uint(v)) << 32) | (unsigned)(~i);
            }
        }
        __syncthreads();
        if (tid == 0) {
            unsigned need = TOPK - Kp, got = 0;
            for (int i = 0; i < 8000 && got < need; ++i)
                if (cs[i] <= -0.5f) { buf[Kp + got] = (unsigned)(~i); got++; }
        }
    }
    __syncthreads();

    // rank-by-count epilogue (keys unique via distinct ~i)
    const int M2 = (Kp >= TOPK) ? (int)min(sh_cnt, 512u) : (int)TOPK;
    for (int i = tid; i < M2; i += 256) {
        unsigned long long key = buf[i];
        int rank = 0;
        for (int j = 0; j < M2; ++j) rank += (buf[j] > key);
        if (rank < TOPK) {
            int fi = (int)(~(unsigned)key);
            int c = fi / TOPK; int kk = fi - c * TOPK;
            float4 bb = top_b[((size_t)b * NCLS + c) * TOPK + kk];
            int base = (b * TOPK + rank) * 6;
            out[base + 0] = bb.x; out[base + 1] = bb.y;
            out[base + 2] = bb.z; out[base + 3] = bb.w;
            out[base + 4] = cs[fi]; out[base + 5] = (float)c;
        }
    }
}

// ---------------------------------------------------------------------------
extern "C" void kernel_launch(void* const* d_in, const int* in_sizes, int n_in,
                              void* d_out, int out_size, void* d_ws, size_t ws_size,
                              hipStream_t stream) {
    (void)n_in; (void)out_size; (void)ws_size;
    const float* f0      = (const float*)d_in[0];
    const float* f1      = (const float*)d_in[1];
    const float* f2      = (const float*)d_in[2];
    const float* anchors = (const float*)d_in[3];
    const float* imshape = (const float*)d_in[4];
    const int B = in_sizes[0] / (255 * 19 * 19);

    char* ws = (char*)d_ws;
    size_t o = 0;
    float4* boxes  = (float4*)(ws + o); o += (size_t)B * NTOT * sizeof(float4);
    float*  conf_q = (float*)(ws + o);  o += (size_t)B * KPAD * sizeof(float);
    float4* top_b  = (float4*)(ws + o); o += (size_t)B * NCLS * TOPK * sizeof(float4);
    float*  cand   = (float*)(ws + o);  o += (size_t)B * NCLS * TOPK * sizeof(float);
    float*  out    = (float*)d_out;

    const int total = B * NTOT;
    k_decode<<<(total + 255) / 256, 256, 0, stream>>>(f0, f1, f2, anchors, imshape,
                                                      boxes, conf_q, total);
    k_topk<<<B * NCLS, 512, 0, stream>>>(f0, f1, f2, conf_q, boxes,
                                         top_b, cand);
    k_final<<<B, 256, 0, stream>>>(cand, top_b, out);
}